// Round 8
// baseline (695.631 us; speedup 1.0000x reference)
//
#include <hip/hip_runtime.h>
#include <stdint.h>
#include <math.h>

#define T_SEQ 2048
#define D_MODEL 1024
#define NHEAD 16
#define DH 64
#define F_FF 4096
#define TP (T_SEQ + 2)   // per-batch padded rows for causal conv (2 leading zero rows)

typedef unsigned short u16;
typedef float f32x4 __attribute__((ext_vector_type(4)));
typedef __bf16 bf16x8 __attribute__((ext_vector_type(8)));

__device__ __forceinline__ u16 f2bf(float f){
  unsigned u = __float_as_uint(f);
  u = u + 0x7fffu + ((u >> 16) & 1u);   // RNE
  return (u16)(u >> 16);
}
__device__ __forceinline__ float b2f(u16 h){ return __uint_as_float(((unsigned)h) << 16); }

// gelu(tanh approx) = x * sigmoid(2u), u = c(x + 0.044715 x^3).
__device__ __forceinline__ float gelu_f(float x){
  const float c = 0.7978845608028654f; // sqrt(2/pi)
  float u = c * (x + 0.044715f * x * x * x);
  float e = __expf(-2.0f * u);
  return x * __builtin_amdgcn_rcpf(1.0f + e);
}

#define AS1 __attribute__((address_space(1)))
#define AS3 __attribute__((address_space(3)))
__device__ __forceinline__ void async_cp16(void* lds, const void* g){
  __builtin_amdgcn_global_load_lds((AS1 void*)(void*)g, (AS3 void*)lds, 16, 0, 0);
}

// flagged load: element i of a float tensor that is either bf16 (flag=1) or fp32
__device__ __forceinline__ float fload(const void* p, size_t i, unsigned isbf){
  return isbf ? b2f(((const u16*)p)[i]) : ((const float*)p)[i];
}

// ---------------------------------------------------------------------------
__global__ void detect_dtype(const u16* __restrict__ x, unsigned* __restrict__ flags){
  unsigned e = ((unsigned)x[threadIdx.x] >> 7) & 0xFF;
  bool good = (e == 0 || (e >= 90 && e <= 150));
  unsigned long long b = __ballot(good);
  if (threadIdx.x == 0) flags[0] = (b == ~0ULL) ? 1u : 0u;
}

// ---------------------------------------------------------------------------
__global__ __launch_bounds__(256) void canon_mask(const unsigned char* __restrict__ raw,
                                                  unsigned char* __restrict__ canon){
  int i = blockIdx.x * 256 + threadIdx.x;
  if (i >= 2 * T_SEQ) return;
  unsigned char v;
  if (raw[3584]) {
    v = raw[i] != 0;
  } else if (raw[7168]) {
    v = ((const u16*)raw)[i] != 0;
  } else if (raw[14336]) {
    v = ((const int*)raw)[i] != 0;
  } else {
    v = ((const long long*)raw)[i] != 0;
  }
  canon[i] = v;
}

// ---------------------------------------------------------------------------
__global__ __launch_bounds__(256)
void cast_any2bf(const void* __restrict__ in, u16* __restrict__ out, int n,
                 const unsigned* __restrict__ flags){
  int i = (blockIdx.x * 256 + threadIdx.x) * 4;
  if (i >= n) return;
  if (flags[0]){
    *(ushort4*)(out + i) = *(const ushort4*)((const u16*)in + i);
  } else {
    float4 v = *(const float4*)((const float*)in + i);
    ushort4 o = { f2bf(v.x), f2bf(v.y), f2bf(v.z), f2bf(v.w) };
    *(ushort4*)(out + i) = o;
  }
}

__global__ __launch_bounds__(256)
void cast_out(const float* __restrict__ in, const float* __restrict__ res,
              void* __restrict__ out, int n, const unsigned* __restrict__ flags){
  int i = (blockIdx.x * 256 + threadIdx.x) * 4;
  if (i >= n) return;
  float4 v = *(const float4*)(in + i);
  float4 r = *(const float4*)(res + i);
  v.x += r.x; v.y += r.y; v.z += r.z; v.w += r.w;
  if (flags[0]){
    ushort4 o = { f2bf(v.x), f2bf(v.y), f2bf(v.z), f2bf(v.w) };
    *(ushort4*)((u16*)out + i) = o;
  } else {
    *(float4*)((float*)out + i) = v;
  }
}

// ---------------------------------------------------------------------------
template<int INX1>
__global__ __launch_bounds__(256)
void ln_kernel(const void* __restrict__ inv, const void* __restrict__ g,
               const void* __restrict__ be, const void* __restrict__ pos,
               u16* __restrict__ out, int addpos, int padout,
               const unsigned* __restrict__ flags)
{
  const unsigned isbf = flags[0];
  const int r = blockIdx.x;
  const int bb = r >> 11, tt = r & (T_SEQ - 1);
  const size_t ib = (size_t)r * D_MODEL + threadIdx.x * 4;
  float v0, v1, v2, v3;
  if (INX1){
    float4 v = *(const float4*)((const float*)inv + ib);
    v0 = v.x; v1 = v.y; v2 = v.z; v3 = v.w;
  } else if (isbf){
    ushort4 u = *(const ushort4*)((const u16*)inv + ib);
    v0 = b2f(u.x); v1 = b2f(u.y); v2 = b2f(u.z); v3 = b2f(u.w);
  } else {
    float4 v = *(const float4*)((const float*)inv + ib);
    v0 = v.x; v1 = v.y; v2 = v.z; v3 = v.w;
  }
  float s  = v0 + v1 + v2 + v3;
  float s2 = v0*v0 + v1*v1 + v2*v2 + v3*v3;
  #pragma unroll
  for (int o = 1; o < 64; o <<= 1){ s += __shfl_xor(s, o); s2 += __shfl_xor(s2, o); }
  __shared__ float w1[4], w2[4];
  int w = threadIdx.x >> 6;
  if ((threadIdx.x & 63) == 0){ w1[w] = s; w2[w] = s2; }
  __syncthreads();
  float S  = w1[0] + w1[1] + w1[2] + w1[3];
  float S2 = w2[0] + w2[1] + w2[2] + w2[3];
  float mu  = S * (1.f / 1024.f);
  float var = S2 * (1.f / 1024.f) - mu * mu;
  float rs  = rsqrtf(var + 1e-5f);
  int d0 = threadIdx.x * 4;
  float o0 = (v0 - mu) * rs * fload(g, d0 + 0, isbf) + fload(be, d0 + 0, isbf);
  float o1 = (v1 - mu) * rs * fload(g, d0 + 1, isbf) + fload(be, d0 + 1, isbf);
  float o2 = (v2 - mu) * rs * fload(g, d0 + 2, isbf) + fload(be, d0 + 2, isbf);
  float o3 = (v3 - mu) * rs * fload(g, d0 + 3, isbf) + fload(be, d0 + 3, isbf);
  if (addpos){
    size_t pb = (size_t)tt * D_MODEL + d0;
    o0 += fload(pos, pb + 0, isbf);
    o1 += fload(pos, pb + 1, isbf);
    o2 += fload(pos, pb + 2, isbf);
    o3 += fload(pos, pb + 3, isbf);
  }
  size_t orow = padout ? ((size_t)bb * TP + tt + 2) * (size_t)D_MODEL
                       : (size_t)r * D_MODEL;
  ushort4 ov = { f2bf(o0), f2bf(o1), f2bf(o2), f2bf(o3) };
  *(ushort4*)(out + orow + d0) = ov;
}

// ---------------------------------------------------------------------------
__global__ __launch_bounds__(256)
void conv_w_split(const void* __restrict__ in, u16* __restrict__ out, int lg2C,
                  const unsigned* __restrict__ flags){
  int i = blockIdx.x * 256 + threadIdx.x;
  if (i >= 4096 * 1024) return;
  const unsigned isbf = flags[0];
  const int C = 1 << lg2C;
  int c = i & (C - 1);
  size_t sb = (size_t)i * 3;
  size_t ob = (size_t)(i >> lg2C) * 3 * C + c;
  out[ob]         = f2bf(fload(in, sb + 0, isbf));
  out[ob + C]     = f2bf(fload(in, sb + 1, isbf));
  out[ob + 2 * C] = f2bf(fload(in, sb + 2, isbf));
}

__global__ __launch_bounds__(256)
void zero_pads(u16* __restrict__ h2pad, u16* __restrict__ g1pad){
  int tid = blockIdx.x * 256 + threadIdx.x;
  if (tid < 2 * 2 * D_MODEL){
    int b = tid >> 11; int off = tid & (2 * D_MODEL - 1);
    h2pad[(size_t)b * TP * D_MODEL + off] = 0;
  }
  if (tid < 2 * 2 * F_FF){
    int b = tid >> 13; int off = tid & (2 * F_FF - 1);
    g1pad[(size_t)b * TP * F_FF + off] = 0;
  }
}

// ---------------------------------------------------------------------------
__device__ __forceinline__ int swz(int tid){          // staging chunk for slot tid
  return (tid & 3) ^ ((tid >> 2) & 3) ^ ((tid >> 4) & 3);
}

// ---------------------------------------------------------------------------
// Legacy 128x128 GEMM (m97-class 2-barrier structure). Still used for
// qkv (MODE 0) and wo (MODE 1).
template<int MODE>
__global__ __launch_bounds__(256)
void gemm_bt(const u16* __restrict__ A, const u16* __restrict__ B,
             const void* __restrict__ res, void* __restrict__ outp,
             int N, int Kin, int lg2Kin, int nseg, long Abstride,
             const unsigned* __restrict__ flags)
{
  __shared__ u16 smA[128 * 32];
  __shared__ u16 smB[128 * 32];
  const int tid = threadIdx.x;
  const int m0 = blockIdx.y * 128;
  const int n0 = blockIdx.x * 128;
  const int Ktot = Kin * nseg;

  const int ch = swz(tid);                 // pre-swizzled source chunk
  long abase[2]; const u16* bbase[2];
  #pragma unroll
  for (int i = 0; i < 2; ++i){
    int r = m0 + i * 64 + (tid >> 2);
    int bb = r >> 11, tt = r & (T_SEQ - 1);
    abase[i] = (long)bb * Abstride + (long)tt * Kin + ch * 8;
    bbase[i] = B + (long)(n0 + i * 64 + (tid >> 2)) * Ktot + ch * 8;
  }

  f32x4 acc[4][4];
  #pragma unroll
  for (int i = 0; i < 4; ++i)
    #pragma unroll
    for (int j = 0; j < 4; ++j){ f32x4 z = {0.f,0.f,0.f,0.f}; acc[i][j] = z; }

  const int wm = (tid >> 6) & 1, wn = (tid >> 7) & 1;
  const int lane = tid & 63, lq = lane >> 4, lr = lane & 15;
  const int xq = lq ^ (lr & 3) ^ (lr >> 2);           // read-side swizzle
  const int aoff = (wm * 64 + lr) * 32 + xq * 8;
  const int boff = (wn * 64 + lr) * 32 + xq * 8;

  for (int k0 = 0; k0 < Ktot; k0 += 32){
    int seg = k0 >> lg2Kin;
    int j0  = k0 & (Kin - 1);
    long aso = (long)seg * Kin + j0;
    long bso = k0;
    #pragma unroll
    for (int i = 0; i < 2; ++i){
      async_cp16(&smA[i * 2048 + tid * 8], A + abase[i] + aso);
      async_cp16(&smB[i * 2048 + tid * 8], bbase[i] + bso);
    }
    __syncthreads();
    bf16x8 af[4], bfv[4];
    #pragma unroll
    for (int mi = 0; mi < 4; ++mi) af[mi]  = *(const bf16x8*)&smA[aoff + mi * 512];
    #pragma unroll
    for (int ni = 0; ni < 4; ++ni) bfv[ni] = *(const bf16x8*)&smB[boff + ni * 512];
    #pragma unroll
    for (int mi = 0; mi < 4; ++mi)
      #pragma unroll
      for (int ni = 0; ni < 4; ++ni)
        acc[mi][ni] = __builtin_amdgcn_mfma_f32_16x16x32_bf16(af[mi], bfv[ni], acc[mi][ni], 0, 0, 0);
    __syncthreads();
  }

  const unsigned isbf = (MODE == 1 || MODE == 3) ? flags[0] : 0;
  #pragma unroll
  for (int mi = 0; mi < 4; ++mi){
    #pragma unroll
    for (int ni = 0; ni < 4; ++ni){
      int row0 = m0 + wm * 64 + mi * 16 + lq * 4;
      int col  = n0 + wn * 64 + ni * 16 + lr;
      if (MODE == 0){
        ushort4 pv = { f2bf(acc[mi][ni][0]), f2bf(acc[mi][ni][1]),
                       f2bf(acc[mi][ni][2]), f2bf(acc[mi][ni][3]) };
        if (col < 2 * D_MODEL){
          #pragma unroll
          for (int rr = 0; rr < 4; ++rr)
            ((u16*)outp)[(size_t)(row0 + rr) * N + col] = ((const u16*)&pv)[rr];
        } else {
          int hh = (col - 2 * D_MODEL) >> 6, dd = (col - 2 * D_MODEL) & 63;
          int bb = row0 >> 11, tt = row0 & (T_SEQ - 1);
          *(ushort4*)((u16*)const_cast<void*>(res) +
                      ((size_t)(bb * NHEAD + hh) * 64 + dd) * T_SEQ + tt) = pv;
        }
      } else {
        #pragma unroll
        for (int rr = 0; rr < 4; ++rr){
          int row = row0 + rr;
          float v = acc[mi][ni][rr];
          size_t idx = (size_t)row * N + col;
          if (MODE == 1){
            ((float*)outp)[idx] = v + fload(res, idx, isbf);
          } else if (MODE == 3){
            float ov = v + ((const float*)res)[idx];
            if (isbf) ((u16*)outp)[idx] = f2bf(ov);
            else      ((float*)outp)[idx] = ov;
          }
        }
      }
    }
  }
}

// ---------------------------------------------------------------------------
// gemm4: 128x128 tile, 256 thr = 4 waves (2m x 2n, 64x64 each), ring-2 LDS
// (2 x 16 KB = 32 KiB -> up to 4 blocks/CU), depth-1 counted prefetch,
// SINGLE barrier per K-tile, XCD-locality decode. The occupancy play: at
// 1 block/CU (R7) all 8 waves convoy on one barrier domain; here 3-4
// independent blocks/CU hide each other's vmcnt+barrier drains (m114).
// Buffer-reuse safety: stage of kt+1 -> buf^1 (read during kt-1) is issued
// after the kt-top barrier; any wave past that barrier has COMPLETED its
// kt-1 reads (they were consumed by its kt-1 MFMAs via lgkmcnt).
// MODE 2: bf16 gelu(acc) into (TP)-padded layout (conv1).
// MODE 4: split-K partial, fp32 atomicAdd into zero-seeded accumulator (conv2).
template<int MODE>
__global__ __launch_bounds__(256, 4)
void gemm4(const u16* __restrict__ A, const u16* __restrict__ Bm,
           void* __restrict__ outp, int N, int Kin, int Ktot, int nkt, long Abstride)
{
  __shared__ u16 L[2][8192];   // per buf: [A 128x32 | B 128x32] = 16 KB
  const int tid = threadIdx.x;

  // XCD-locality decode (hardware: XCD = bid % 8), grid = 1024
  const int bid = blockIdx.x;
  const int xcd = bid & 7, idx = bid >> 3;       // idx 0..127
  int bx, by, kz;
  if (MODE == 2){ bx = xcd * 4 + (idx & 3); by = idx >> 2; kz = 0; }          // 32n x 32m
  else          { kz = xcd >> 1; bx = idx & 7; by = ((xcd & 1) << 4) + (idx >> 3); } // 8n x 32m x 4k
  const int m0 = by * 128, n0 = bx * 128;
  const int kt0 = kz * nkt;
  const int ktEnd = kt0 + nkt;

  // staging: thread t -> rows (t>>2) and 64+(t>>2), chunk pos t&3 holds
  // global chunk swz(t); LDS dst linear (global_load_lds requirement)
  const int ch = swz(tid);
  int asrc[2]; const u16* bsrc[2];
  #pragma unroll
  for (int i = 0; i < 2; ++i){
    int r = m0 + i * 64 + (tid >> 2);
    int bb = r >> 11, tt = r & (T_SEQ - 1);
    asrc[i] = bb * (int)Abstride + tt * Kin + ch * 8;
    bsrc[i] = Bm + (long)(n0 + i * 64 + (tid >> 2)) * Ktot + ch * 8;
  }

  const int w = tid >> 6, lane = tid & 63;
  const int wm = w >> 1, wn = w & 1;
  const int quad = lane >> 4, lr = lane & 15;
  const int xq = quad ^ (lr & 3) ^ (lr >> 2);   // read-side swizzle
  const int aoff = (wm * 64 + lr) * 32 + xq * 8;
  const int boff = 4096 + (wn * 64 + lr) * 32 + xq * 8;

  f32x4 acc[4][4];
  #pragma unroll
  for (int i = 0; i < 4; ++i)
    #pragma unroll
    for (int j = 0; j < 4; ++j){ f32x4 z = {0.f,0.f,0.f,0.f}; acc[i][j] = z; }

  // prologue: stage kt0 into buf 0
  #pragma unroll
  for (int i = 0; i < 2; ++i){
    async_cp16(&L[0][i * 2048 + tid * 8], A + asrc[i] + (long)kt0 * 32);
    async_cp16(&L[0][4096 + i * 2048 + tid * 8], bsrc[i] + (long)kt0 * 32);
  }

  for (int kt = kt0; kt < ktEnd; ++kt){
    const int b = (kt - kt0) & 1;
    asm volatile("s_waitcnt vmcnt(0)" ::: "memory");
    __builtin_amdgcn_s_barrier();
    __builtin_amdgcn_sched_barrier(0);
    const u16* Lp = L[b];
    bf16x8 af[4], bfv[4];
    #pragma unroll
    for (int mi = 0; mi < 4; ++mi) af[mi]  = *(const bf16x8*)&Lp[aoff + mi * 512];
    #pragma unroll
    for (int ni = 0; ni < 4; ++ni) bfv[ni] = *(const bf16x8*)&Lp[boff + ni * 512];
    if (kt + 1 < ktEnd){
      u16* Ld = L[b ^ 1];
      #pragma unroll
      for (int i = 0; i < 2; ++i){
        async_cp16(&Ld[i * 2048 + tid * 8], A + asrc[i] + (long)(kt + 1) * 32);
        async_cp16(&Ld[4096 + i * 2048 + tid * 8], bsrc[i] + (long)(kt + 1) * 32);
      }
    }
    __builtin_amdgcn_s_setprio(1);
    #pragma unroll
    for (int mi = 0; mi < 4; ++mi)
      #pragma unroll
      for (int ni = 0; ni < 4; ++ni)
        acc[mi][ni] = __builtin_amdgcn_mfma_f32_16x16x32_bf16(af[mi], bfv[ni], acc[mi][ni], 0, 0, 0);
    __builtin_amdgcn_s_setprio(0);
  }

  // epilogue
  #pragma unroll
  for (int mi = 0; mi < 4; ++mi){
    #pragma unroll
    for (int ni = 0; ni < 4; ++ni){
      int col = n0 + wn * 64 + ni * 16 + lr;
      #pragma unroll
      for (int rr = 0; rr < 4; ++rr){
        int row = m0 + wm * 64 + mi * 16 + quad * 4 + rr;
        if (MODE == 2){
          int bb = row >> 11, tt = row & (T_SEQ - 1);
          ((u16*)outp)[((size_t)(bb * TP + tt + 2)) * N + col] = f2bf(gelu_f(acc[mi][ni][rr]));
        } else {
          atomicAdd((float*)outp + (size_t)row * N + col, acc[mi][ni][rr]);
        }
      }
    }
  }
}

// ---------------------------------------------------------------------------
// MFMA flash attention (unchanged).
__global__ __launch_bounds__(256)
void attn_mfma(const u16* __restrict__ qkv, const u16* __restrict__ vT,
               const unsigned char* __restrict__ mask, u16* __restrict__ y)
{
  const int qb = blockIdx.x, h = blockIdx.y, b = blockIdx.z;
  const int q0 = qb * 64;
  const int tid = threadIdx.x;

  if (mask[b * T_SEQ + q0]){
    int r = tid >> 2, c4 = (tid & 3) * 16;
    u16* yp = y + (size_t)(b * T_SEQ + q0 + r) * D_MODEL + h * DH + c4;
    ushort4 z = {0, 0, 0, 0};
    #pragma unroll
    for (int c = 0; c < 4; ++c) *(ushort4*)(yp + c * 4) = z;
    return;
  }

  const int w = tid >> 6, lane = tid & 63;
  const int quad = lane >> 4, lr = lane & 15;

  __shared__ u16 Ks[64 * 72];
  __shared__ u16 Vs[64 * 72];
  __shared__ u16 Ps[64 * 72];

  bf16x8 aq0, aq1;
  {
    const u16* qp = qkv + (size_t)(b * T_SEQ + q0 + w * 16 + lr) * 3072 + h * DH + quad * 8;
    aq0 = *(const bf16x8*)qp;
    aq1 = *(const bf16x8*)(qp + 32);
  }

  f32x4 acc_o[4];
  #pragma unroll
  for (int i = 0; i < 4; ++i){ f32x4 z = {0.f,0.f,0.f,0.f}; acc_o[i] = z; }
  float mrow[4] = {-1e30f, -1e30f, -1e30f, -1e30f};
  float lrow[4] = {0.f, 0.f, 0.f, 0.f};

  const int sr = tid >> 3, sg = tid & 7;

  for (int it = 0; it <= qb; ++it){
    const int s0 = it * 64;
    #pragma unroll
    for (int rr = 0; rr < 64; rr += 32){
      int row = sr + rr;
      *(uint4*)&Ks[row * 72 + sg * 8] =
        *(const uint4*)(qkv + (size_t)(b * T_SEQ + s0 + row) * 3072 + D_MODEL + h * DH + sg * 8);
      *(uint4*)&Vs[row * 72 + sg * 8] =
        *(const uint4*)(vT + ((size_t)(b * NHEAD + h) * 64 + row) * T_SEQ + s0 + sg * 8);
    }
    __syncthreads();

    f32x4 accs[4];
    #pragma unroll
    for (int nt = 0; nt < 4; ++nt){
      f32x4 z = {0.f, 0.f, 0.f, 0.f};
      bf16x8 bk0 = *(const bf16x8*)&Ks[(nt * 16 + lr) * 72 + quad * 8];
      bf16x8 bk1 = *(const bf16x8*)&Ks[(nt * 16 + lr) * 72 + quad * 8 + 32];
      z = __builtin_amdgcn_mfma_f32_16x16x32_bf16(aq0, bk0, z, 0, 0, 0);
      z = __builtin_amdgcn_mfma_f32_16x16x32_bf16(aq1, bk1, z, 0, 0, 0);
      accs[nt] = z;
    }

    const bool diag = (it == qb);
    float sv[4][4], mx[4];
    #pragma unroll
    for (int rr = 0; rr < 4; ++rr) mx[rr] = -1e30f;
    #pragma unroll
    for (int nt = 0; nt < 4; ++nt){
      #pragma unroll
      for (int rr = 0; rr < 4; ++rr){
        float s = accs[nt][rr] * 0.125f;
        if (diag && (nt * 16 + lr) > (w * 16 + quad * 4 + rr)) s = -1e30f;
        sv[nt][rr] = s;
        mx[rr] = fmaxf(mx[rr], s);
      }
    }
    #pragma unroll
    for (int o = 1; o < 16; o <<= 1){
      #pragma unroll
      for (int rr = 0; rr < 4; ++rr) mx[rr] = fmaxf(mx[rr], __shfl_xor(mx[rr], o));
    }
    float alpha[4], psum[4];
    #pragma unroll
    for (int rr = 0; rr < 4; ++rr){
      float mnew = fmaxf(mrow[rr], mx[rr]);
      alpha[rr] = __expf(mrow[rr] - mnew);
      mrow[rr] = mnew;
      psum[rr] = 0.f;
    }
    #pragma unroll
    for (int nt = 0; nt < 4; ++nt){
      #pragma unroll
      for (int rr = 0; rr < 4; ++rr){
        float p = __expf(sv[nt][rr] - mrow[rr]);
        psum[rr] += p;
        Ps[(w * 16 + quad * 4 + rr) * 72 + nt * 16 + lr] = f2bf(p);
      }
    }
    #pragma unroll
    for (int o = 1; o < 16; o <<= 1){
      #pragma unroll
      for (int rr = 0; rr < 4; ++rr) psum[rr] += __shfl_xor(psum[rr], o);
    }
    #pragma unroll
    for (int rr = 0; rr < 4; ++rr) lrow[rr] = lrow[rr] * alpha[rr] + psum[rr];
    #pragma unroll
    for (int nt = 0; nt < 4; ++nt)
      #pragma unroll
      for (int rr = 0; rr < 4; ++rr) acc_o[nt][rr] *= alpha[rr];

    bf16x8 ap0 = *(const bf16x8*)&Ps[(w * 16 + lr) * 72 + quad * 8];
    bf16x8 ap1 = *(const bf16x8*)&Ps[(w * 16 + lr) * 72 + quad * 8 + 32];
    #pragma unroll
    for (int nt = 0; nt < 4; ++nt){
      bf16x8 bv0 = *(const bf16x8*)&Vs[(nt * 16 + lr) * 72 + quad * 8];
      bf16x8 bv1 = *(const bf16x8*)&Vs[(nt * 16 + lr) * 72 + quad * 8 + 32];
      acc_o[nt] = __builtin_amdgcn_mfma_f32_16x16x32_bf16(ap0, bv0, acc_o[nt], 0, 0, 0);
      acc_o[nt] = __builtin_amdgcn_mfma_f32_16x16x32_bf16(ap1, bv1, acc_o[nt], 0, 0, 0);
    }
    __syncthreads();
  }

  #pragma unroll
  for (int rr = 0; rr < 4; ++rr){
    int qg = q0 + w * 16 + quad * 4 + rr;
    float inv = 1.0f / lrow[rr];
    bool rm = mask[b * T_SEQ + qg] != 0;
    #pragma unroll
    for (int nt = 0; nt < 4; ++nt){
      float v = rm ? 0.f : acc_o[nt][rr] * inv;
      y[(size_t)(b * T_SEQ + qg) * D_MODEL + h * DH + nt * 16 + lr] = f2bf(v);
    }
  }
}

// ---------------------------------------------------------------------------
extern "C" void kernel_launch(void* const* d_in, const int* in_sizes, int n_in,
                              void* d_out, int out_size, void* d_ws, size_t ws_size,
                              hipStream_t stream)
{
  const void* x       = d_in[0];
  const unsigned char* xmask_raw = (const unsigned char*)d_in[1];
  const void* pos     = d_in[2];
  const void* w_qkv   = d_in[3];
  const void* w_o     = d_in[4];
  const void* ln1_g   = d_in[5];
  const void* ln1_b   = d_in[6];
  const void* ln2_g   = d_in[7];
  const void* ln2_b   = d_in[8];
  const void* conv1_w = d_in[9];
  const void* conv2_w = d_in[10];

  char* ws = (char*)d_ws;
  size_t o = 0;
  auto alloc = [&](size_t bytes){ size_t cur = o; o += (bytes + 255) & ~(size_t)255; return cur; };
  unsigned* flags = (unsigned*)(ws + alloc(256));
  unsigned char* maskc = (unsigned char*)(ws + alloc(2 * T_SEQ));
  float* x1   = (float*)(ws + alloc((size_t)2 * T_SEQ * D_MODEL * 4));
  char* h2slab = ws + alloc((size_t)2 * TP * D_MODEL * 2);
  u16* g1pad  = (u16*)(ws + alloc((size_t)2 * TP * F_FF * 2));
  u16* slabA  = (u16*)(ws + alloc((size_t)4096 * 3072 * 2));
  u16* qy     = (u16*)(ws + alloc((size_t)4096 * 1024 * 2));
  char* vslab = ws + alloc((size_t)4096 * 1024 * 4);
  u16* vt     = (u16*)vslab;
  float* xc   = (float*)vslab;

  u16* wqkv_c = (u16*)h2slab;
  u16* wo_c   = (u16*)h2slab + (size_t)3072 * 1024;
  u16* h2pad  = (u16*)h2slab;
  u16* qin    = qy;
  u16* qkvb   = slabA;
  u16* yb     = qy;
  u16* W1cat  = slabA;
  u16* W2cat  = slabA;

  detect_dtype<<<1, 64, 0, stream>>>((const u16*)x, flags);
  canon_mask<<<16, 256, 0, stream>>>(xmask_raw, maskc);
  cast_any2bf<<<3072 * 1024 / 4 / 256, 256, 0, stream>>>(w_qkv, wqkv_c, 3072 * 1024, flags);
  cast_any2bf<<<1024 * 1024 / 4 / 256, 256, 0, stream>>>(w_o, wo_c, 1024 * 1024, flags);
  ln_kernel<0><<<4096, 256, 0, stream>>>(x, ln1_g, ln1_b, pos, qin, 1, 0, flags);
  gemm_bt<0><<<dim3(24, 32), 256, 0, stream>>>(qin, wqkv_c, vt, qkvb,
                                               3072, 1024, 10, 1, (long)T_SEQ * 1024, flags);
  attn_mfma<<<dim3(32, 16, 2), 256, 0, stream>>>(qkvb, vt, maskc, yb);
  gemm_bt<1><<<dim3(8, 32), 256, 0, stream>>>(yb, wo_c, x, x1,
                                              1024, 1024, 10, 1, (long)T_SEQ * 1024, flags);
  hipMemsetAsync(xc, 0, (size_t)4096 * 1024 * 4, stream);
  conv_w_split<<<4096 * 1024 / 256, 256, 0, stream>>>(conv1_w, W1cat, 10, flags);
  zero_pads<<<64, 256, 0, stream>>>(h2pad, g1pad);
  ln_kernel<1><<<4096, 256, 0, stream>>>(x1, ln2_g, ln2_b, nullptr, h2pad, 0, 1, flags);
  // g1 = gelu(causal_conv1(h2)) : 128x128 multi-block pipelined GEMM,
  // grid 1024 (32n x 32m via XCD decode), 3-4 blocks/CU.
  gemm4<2><<<dim3(1024, 1, 1), 256, 0, stream>>>(h2pad, W1cat, g1pad,
                                                 4096, 1024, 3072, 96, (long)TP * 1024);
  conv_w_split<<<4096 * 1024 / 256, 256, 0, stream>>>(conv2_w, W2cat, 12, flags);
  // conv2 as plain linear-K GEMM, split-K x4 (grid 1024 via XCD decode).
  gemm4<4><<<dim3(1024, 1, 1), 256, 0, stream>>>(g1pad, W2cat, xc,
                                                 1024, 4096, 12288, 96, (long)TP * 4096);
  cast_out<<<4096 * 1024 / 4 / 256, 256, 0, stream>>>(xc, x1, d_out, 4096 * 1024, flags);
}

// Round 9
// 603.782 us; speedup vs baseline: 1.1521x; 1.1521x over previous
//
#include <hip/hip_runtime.h>
#include <stdint.h>
#include <math.h>

#define T_SEQ 2048
#define D_MODEL 1024
#define NHEAD 16
#define DH 64
#define F_FF 4096
#define TP (T_SEQ + 2)   // per-batch padded rows for causal conv (2 leading zero rows)

typedef unsigned short u16;
typedef float f32x4 __attribute__((ext_vector_type(4)));
typedef __bf16 bf16x8 __attribute__((ext_vector_type(8)));

__device__ __forceinline__ u16 f2bf(float f){
  unsigned u = __float_as_uint(f);
  u = u + 0x7fffu + ((u >> 16) & 1u);   // RNE
  return (u16)(u >> 16);
}
__device__ __forceinline__ float b2f(u16 h){ return __uint_as_float(((unsigned)h) << 16); }

// gelu(tanh approx) = x * sigmoid(2u), u = c(x + 0.044715 x^3).
__device__ __forceinline__ float gelu_f(float x){
  const float c = 0.7978845608028654f; // sqrt(2/pi)
  float u = c * (x + 0.044715f * x * x * x);
  float e = __expf(-2.0f * u);
  return x * __builtin_amdgcn_rcpf(1.0f + e);
}

#define AS1 __attribute__((address_space(1)))
#define AS3 __attribute__((address_space(3)))
__device__ __forceinline__ void async_cp16(void* lds, const void* g){
  __builtin_amdgcn_global_load_lds((AS1 void*)(void*)g, (AS3 void*)lds, 16, 0, 0);
}

// flagged load: element i of a float tensor that is either bf16 (flag=1) or fp32
__device__ __forceinline__ float fload(const void* p, size_t i, unsigned isbf){
  return isbf ? b2f(((const u16*)p)[i]) : ((const float*)p)[i];
}

// ---------------------------------------------------------------------------
__global__ void detect_dtype(const u16* __restrict__ x, unsigned* __restrict__ flags){
  unsigned e = ((unsigned)x[threadIdx.x] >> 7) & 0xFF;
  bool good = (e == 0 || (e >= 90 && e <= 150));
  unsigned long long b = __ballot(good);
  if (threadIdx.x == 0) flags[0] = (b == ~0ULL) ? 1u : 0u;
}

// ---------------------------------------------------------------------------
__global__ __launch_bounds__(256) void canon_mask(const unsigned char* __restrict__ raw,
                                                  unsigned char* __restrict__ canon){
  int i = blockIdx.x * 256 + threadIdx.x;
  if (i >= 2 * T_SEQ) return;
  unsigned char v;
  if (raw[3584]) {
    v = raw[i] != 0;
  } else if (raw[7168]) {
    v = ((const u16*)raw)[i] != 0;
  } else if (raw[14336]) {
    v = ((const int*)raw)[i] != 0;
  } else {
    v = ((const long long*)raw)[i] != 0;
  }
  canon[i] = v;
}

// ---------------------------------------------------------------------------
__global__ __launch_bounds__(256)
void cast_any2bf(const void* __restrict__ in, u16* __restrict__ out, int n,
                 const unsigned* __restrict__ flags){
  int i = (blockIdx.x * 256 + threadIdx.x) * 4;
  if (i >= n) return;
  if (flags[0]){
    *(ushort4*)(out + i) = *(const ushort4*)((const u16*)in + i);
  } else {
    float4 v = *(const float4*)((const float*)in + i);
    ushort4 o = { f2bf(v.x), f2bf(v.y), f2bf(v.z), f2bf(v.w) };
    *(ushort4*)(out + i) = o;
  }
}

__global__ __launch_bounds__(256)
void cast_out(const float* __restrict__ in, const float* __restrict__ res,
              void* __restrict__ out, int n, const unsigned* __restrict__ flags){
  int i = (blockIdx.x * 256 + threadIdx.x) * 4;
  if (i >= n) return;
  float4 v = *(const float4*)(in + i);
  float4 r = *(const float4*)(res + i);
  v.x += r.x; v.y += r.y; v.z += r.z; v.w += r.w;
  if (flags[0]){
    ushort4 o = { f2bf(v.x), f2bf(v.y), f2bf(v.z), f2bf(v.w) };
    *(ushort4*)((u16*)out + i) = o;
  } else {
    *(float4*)((float*)out + i) = v;
  }
}

// ---------------------------------------------------------------------------
template<int INX1>
__global__ __launch_bounds__(256)
void ln_kernel(const void* __restrict__ inv, const void* __restrict__ g,
               const void* __restrict__ be, const void* __restrict__ pos,
               u16* __restrict__ out, int addpos, int padout,
               const unsigned* __restrict__ flags)
{
  const unsigned isbf = flags[0];
  const int r = blockIdx.x;
  const int bb = r >> 11, tt = r & (T_SEQ - 1);
  const size_t ib = (size_t)r * D_MODEL + threadIdx.x * 4;
  float v0, v1, v2, v3;
  if (INX1){
    float4 v = *(const float4*)((const float*)inv + ib);
    v0 = v.x; v1 = v.y; v2 = v.z; v3 = v.w;
  } else if (isbf){
    ushort4 u = *(const ushort4*)((const u16*)inv + ib);
    v0 = b2f(u.x); v1 = b2f(u.y); v2 = b2f(u.z); v3 = b2f(u.w);
  } else {
    float4 v = *(const float4*)((const float*)inv + ib);
    v0 = v.x; v1 = v.y; v2 = v.z; v3 = v.w;
  }
  float s  = v0 + v1 + v2 + v3;
  float s2 = v0*v0 + v1*v1 + v2*v2 + v3*v3;
  #pragma unroll
  for (int o = 1; o < 64; o <<= 1){ s += __shfl_xor(s, o); s2 += __shfl_xor(s2, o); }
  __shared__ float w1[4], w2[4];
  int w = threadIdx.x >> 6;
  if ((threadIdx.x & 63) == 0){ w1[w] = s; w2[w] = s2; }
  __syncthreads();
  float S  = w1[0] + w1[1] + w1[2] + w1[3];
  float S2 = w2[0] + w2[1] + w2[2] + w2[3];
  float mu  = S * (1.f / 1024.f);
  float var = S2 * (1.f / 1024.f) - mu * mu;
  float rs  = rsqrtf(var + 1e-5f);
  int d0 = threadIdx.x * 4;
  float o0 = (v0 - mu) * rs * fload(g, d0 + 0, isbf) + fload(be, d0 + 0, isbf);
  float o1 = (v1 - mu) * rs * fload(g, d0 + 1, isbf) + fload(be, d0 + 1, isbf);
  float o2 = (v2 - mu) * rs * fload(g, d0 + 2, isbf) + fload(be, d0 + 2, isbf);
  float o3 = (v3 - mu) * rs * fload(g, d0 + 3, isbf) + fload(be, d0 + 3, isbf);
  if (addpos){
    size_t pb = (size_t)tt * D_MODEL + d0;
    o0 += fload(pos, pb + 0, isbf);
    o1 += fload(pos, pb + 1, isbf);
    o2 += fload(pos, pb + 2, isbf);
    o3 += fload(pos, pb + 3, isbf);
  }
  size_t orow = padout ? ((size_t)bb * TP + tt + 2) * (size_t)D_MODEL
                       : (size_t)r * D_MODEL;
  ushort4 ov = { f2bf(o0), f2bf(o1), f2bf(o2), f2bf(o3) };
  *(ushort4*)(out + orow + d0) = ov;
}

// ---------------------------------------------------------------------------
__global__ __launch_bounds__(256)
void conv_w_split(const void* __restrict__ in, u16* __restrict__ out, int lg2C,
                  const unsigned* __restrict__ flags){
  int i = blockIdx.x * 256 + threadIdx.x;
  if (i >= 4096 * 1024) return;
  const unsigned isbf = flags[0];
  const int C = 1 << lg2C;
  int c = i & (C - 1);
  size_t sb = (size_t)i * 3;
  size_t ob = (size_t)(i >> lg2C) * 3 * C + c;
  out[ob]         = f2bf(fload(in, sb + 0, isbf));
  out[ob + C]     = f2bf(fload(in, sb + 1, isbf));
  out[ob + 2 * C] = f2bf(fload(in, sb + 2, isbf));
}

__global__ __launch_bounds__(256)
void zero_pads(u16* __restrict__ h2pad, u16* __restrict__ g1pad){
  int tid = blockIdx.x * 256 + threadIdx.x;
  if (tid < 2 * 2 * D_MODEL){
    int b = tid >> 11; int off = tid & (2 * D_MODEL - 1);
    h2pad[(size_t)b * TP * D_MODEL + off] = 0;
  }
  if (tid < 2 * 2 * F_FF){
    int b = tid >> 13; int off = tid & (2 * F_FF - 1);
    g1pad[(size_t)b * TP * F_FF + off] = 0;
  }
}

// ---------------------------------------------------------------------------
__device__ __forceinline__ int swz(int tid){          // staging chunk for slot tid
  return (tid & 3) ^ ((tid >> 2) & 3) ^ ((tid >> 4) & 3);
}

// ---------------------------------------------------------------------------
// Legacy 128x128 GEMM (m97-class 2-barrier structure). Still used for
// qkv (MODE 0) and wo (MODE 1).
template<int MODE>
__global__ __launch_bounds__(256)
void gemm_bt(const u16* __restrict__ A, const u16* __restrict__ B,
             const void* __restrict__ res, void* __restrict__ outp,
             int N, int Kin, int lg2Kin, int nseg, long Abstride,
             const unsigned* __restrict__ flags)
{
  __shared__ u16 smA[128 * 32];
  __shared__ u16 smB[128 * 32];
  const int tid = threadIdx.x;
  const int m0 = blockIdx.y * 128;
  const int n0 = blockIdx.x * 128;
  const int Ktot = Kin * nseg;

  const int ch = swz(tid);                 // pre-swizzled source chunk
  long abase[2]; const u16* bbase[2];
  #pragma unroll
  for (int i = 0; i < 2; ++i){
    int r = m0 + i * 64 + (tid >> 2);
    int bb = r >> 11, tt = r & (T_SEQ - 1);
    abase[i] = (long)bb * Abstride + (long)tt * Kin + ch * 8;
    bbase[i] = B + (long)(n0 + i * 64 + (tid >> 2)) * Ktot + ch * 8;
  }

  f32x4 acc[4][4];
  #pragma unroll
  for (int i = 0; i < 4; ++i)
    #pragma unroll
    for (int j = 0; j < 4; ++j){ f32x4 z = {0.f,0.f,0.f,0.f}; acc[i][j] = z; }

  const int wm = (tid >> 6) & 1, wn = (tid >> 7) & 1;
  const int lane = tid & 63, lq = lane >> 4, lr = lane & 15;
  const int xq = lq ^ (lr & 3) ^ (lr >> 2);           // read-side swizzle
  const int aoff = (wm * 64 + lr) * 32 + xq * 8;
  const int boff = (wn * 64 + lr) * 32 + xq * 8;

  for (int k0 = 0; k0 < Ktot; k0 += 32){
    int seg = k0 >> lg2Kin;
    int j0  = k0 & (Kin - 1);
    long aso = (long)seg * Kin + j0;
    long bso = k0;
    #pragma unroll
    for (int i = 0; i < 2; ++i){
      async_cp16(&smA[i * 2048 + tid * 8], A + abase[i] + aso);
      async_cp16(&smB[i * 2048 + tid * 8], bbase[i] + bso);
    }
    __syncthreads();
    bf16x8 af[4], bfv[4];
    #pragma unroll
    for (int mi = 0; mi < 4; ++mi) af[mi]  = *(const bf16x8*)&smA[aoff + mi * 512];
    #pragma unroll
    for (int ni = 0; ni < 4; ++ni) bfv[ni] = *(const bf16x8*)&smB[boff + ni * 512];
    #pragma unroll
    for (int mi = 0; mi < 4; ++mi)
      #pragma unroll
      for (int ni = 0; ni < 4; ++ni)
        acc[mi][ni] = __builtin_amdgcn_mfma_f32_16x16x32_bf16(af[mi], bfv[ni], acc[mi][ni], 0, 0, 0);
    __syncthreads();
  }

  const unsigned isbf = (MODE == 1 || MODE == 3) ? flags[0] : 0;
  #pragma unroll
  for (int mi = 0; mi < 4; ++mi){
    #pragma unroll
    for (int ni = 0; ni < 4; ++ni){
      int row0 = m0 + wm * 64 + mi * 16 + lq * 4;
      int col  = n0 + wn * 64 + ni * 16 + lr;
      if (MODE == 0){
        ushort4 pv = { f2bf(acc[mi][ni][0]), f2bf(acc[mi][ni][1]),
                       f2bf(acc[mi][ni][2]), f2bf(acc[mi][ni][3]) };
        if (col < 2 * D_MODEL){
          #pragma unroll
          for (int rr = 0; rr < 4; ++rr)
            ((u16*)outp)[(size_t)(row0 + rr) * N + col] = ((const u16*)&pv)[rr];
        } else {
          int hh = (col - 2 * D_MODEL) >> 6, dd = (col - 2 * D_MODEL) & 63;
          int bb = row0 >> 11, tt = row0 & (T_SEQ - 1);
          *(ushort4*)((u16*)const_cast<void*>(res) +
                      ((size_t)(bb * NHEAD + hh) * 64 + dd) * T_SEQ + tt) = pv;
        }
      } else {
        #pragma unroll
        for (int rr = 0; rr < 4; ++rr){
          int row = row0 + rr;
          float v = acc[mi][ni][rr];
          size_t idx = (size_t)row * N + col;
          if (MODE == 1){
            ((float*)outp)[idx] = v + fload(res, idx, isbf);
          } else if (MODE == 3){
            float ov = v + ((const float*)res)[idx];
            if (isbf) ((u16*)outp)[idx] = f2bf(ov);
            else      ((float*)outp)[idx] = ov;
          }
        }
      }
    }
  }
}

// ---------------------------------------------------------------------------
// 256x256 pipelined GEMM, single-barrier-per-K-tile (R7 best-measured) +
// XCD-locality decode. BK=32, 512 thr = 8 waves, LDS ring 4 x 32KB,
// depth-3 prefetch, vmcnt(8)+barrier once per K-tile.
__device__ __forceinline__ void ktile8(
    f32x4 (&acc)[8][4], u16 (*L)[16384], int buf, int abase, int bbase,
    const u16* __restrict__ A, const long (&asrc)[2], const u16* const (&bsrc)[2],
    const int (&adst)[2], const int (&bdst)[2], int kt, bool stage_ok)
{
  const u16* Lp = L[buf];
  u16* Ld = L[(kt + 3) & 3];
  bf16x8 bfr[4], a0[4], a1[4];
  #pragma unroll
  for (int nf = 0; nf < 4; ++nf) bfr[nf] = *(const bf16x8*)&Lp[bbase + nf * 512];
  #pragma unroll
  for (int j = 0; j < 4; ++j) a0[j] = *(const bf16x8*)&Lp[abase + j * 512];
  if (stage_ok){
    #pragma unroll
    for (int s = 0; s < 2; ++s)
      async_cp16(&Ld[adst[s]], A + asrc[s] + (long)(kt + 3) * 32);
  }
  #pragma unroll
  for (int j = 0; j < 4; ++j) a1[j] = *(const bf16x8*)&Lp[abase + (4 + j) * 512];
  if (stage_ok){
    #pragma unroll
    for (int s = 0; s < 2; ++s)
      async_cp16(&Ld[bdst[s]], bsrc[s] + (long)(kt + 3) * 32);
  }
  __builtin_amdgcn_s_setprio(1);
  #pragma unroll
  for (int j = 0; j < 4; ++j)
    #pragma unroll
    for (int nf = 0; nf < 4; ++nf)
      acc[j][nf] = __builtin_amdgcn_mfma_f32_16x16x32_bf16(a0[j], bfr[nf], acc[j][nf], 0, 0, 0);
  #pragma unroll
  for (int j = 0; j < 4; ++j)
    #pragma unroll
    for (int nf = 0; nf < 4; ++nf)
      acc[4 + j][nf] = __builtin_amdgcn_mfma_f32_16x16x32_bf16(a1[j], bfr[nf], acc[4 + j][nf], 0, 0, 0);
  __builtin_amdgcn_s_setprio(0);
}

// MODE 2: bf16 gelu(acc) into (TP)-padded layout (conv1).
// MODE 4: split-K partial, fp32 atomicAdd into zero-seeded accumulator (conv2).
template<int MODE>
__global__ __launch_bounds__(512, 2)
void gemm8(const u16* __restrict__ A, const u16* __restrict__ Bm,
           void* __restrict__ outp, int N, int Kin, int Ktot, int nkt, long Abstride)
{
  __shared__ u16 L[4][16384];   // 128 KiB ring
  const int tid = threadIdx.x;

  // XCD-locality decode (hardware: XCD = bid % 8), grid = 256
  const int bid = blockIdx.x;
  const int xcd = bid & 7, idx = bid >> 3;
  int bx, by, kz;
  if (MODE == 2){ bx = 2 * xcd + (idx & 1); by = idx >> 1; kz = 0; }
  else          { kz = xcd >> 1; bx = idx & 3; by = ((xcd & 1) << 3) + (idx >> 2); }
  const int m0 = by * 256, n0 = bx * 256;
  const int kt0 = kz * nkt;
  const int ktEnd = kt0 + nkt;

  // staging: slot tid (row tid>>2, pos tid&3) holds global chunk swz(tid)
  const int rl = tid >> 2;
  const int ch = swz(tid);
  long asrc[2]; const u16* bsrc[2]; int adst[2], bdst[2];
  #pragma unroll
  for (int s = 0; s < 2; ++s){
    int r = m0 + s * 128 + rl;
    int bb = r >> 11, tt = r & (T_SEQ - 1);
    asrc[s] = (long)bb * Abstride + (long)tt * Kin + ch * 8;
    bsrc[s] = Bm + (long)(n0 + s * 128 + rl) * Ktot + ch * 8;
    adst[s] = (s * 512 + tid) * 8;
    bdst[s] = 8192 + adst[s];
  }

  const int w = tid >> 6, lane = tid & 63;
  const int wm = w >> 2, wn = w & 3;
  const int quad = lane >> 4, lr = lane & 15;
  const int xq = quad ^ (lr & 3) ^ (lr >> 2);   // read-side swizzle
  const int abase = ((wm * 128 + lr) * 4 + xq) * 8;
  const int bbase = 8192 + ((wn * 64 + lr) * 4 + xq) * 8;

  f32x4 acc[8][4];
  #pragma unroll
  for (int i = 0; i < 8; ++i)
    #pragma unroll
    for (int j = 0; j < 4; ++j){ f32x4 z = {0.f,0.f,0.f,0.f}; acc[i][j] = z; }

  // prologue: stage k-tiles kt0..kt0+2 (oldest-first => vmcnt(8) leaves kt0 complete)
  #pragma unroll
  for (int j = 0; j < 3; ++j){
    #pragma unroll
    for (int s = 0; s < 2; ++s) async_cp16(&L[(kt0 + j) & 3][adst[s]], A + asrc[s] + (long)(kt0 + j) * 32);
    #pragma unroll
    for (int s = 0; s < 2; ++s) async_cp16(&L[(kt0 + j) & 3][bdst[s]], bsrc[s] + (long)(kt0 + j) * 32);
  }

  int kt = kt0;
  for (; kt < ktEnd - 2; ++kt){
    asm volatile("s_waitcnt vmcnt(8)" ::: "memory");  // kt's 4 loads retired; kt+1,kt+2 in flight
    __builtin_amdgcn_s_barrier();
    __builtin_amdgcn_sched_barrier(0);
    ktile8(acc, L, kt & 3, abase, bbase, A, asrc, bsrc, adst, bdst, kt, kt + 3 < ktEnd);
  }
  asm volatile("s_waitcnt vmcnt(4)" ::: "memory");
  __builtin_amdgcn_s_barrier();
  __builtin_amdgcn_sched_barrier(0);
  ktile8(acc, L, (ktEnd - 2) & 3, abase, bbase, A, asrc, bsrc, adst, bdst, ktEnd - 2, false);
  asm volatile("s_waitcnt vmcnt(0)" ::: "memory");
  __builtin_amdgcn_s_barrier();
  __builtin_amdgcn_sched_barrier(0);
  ktile8(acc, L, (ktEnd - 1) & 3, abase, bbase, A, asrc, bsrc, adst, bdst, ktEnd - 1, false);

  // epilogue
  #pragma unroll
  for (int mf = 0; mf < 8; ++mf){
    #pragma unroll
    for (int nf = 0; nf < 4; ++nf){
      int col = n0 + wn * 64 + nf * 16 + lr;
      #pragma unroll
      for (int rr = 0; rr < 4; ++rr){
        int row = m0 + wm * 128 + mf * 16 + quad * 4 + rr;
        if (MODE == 2){
          int bb = row >> 11, tt = row & (T_SEQ - 1);
          ((u16*)outp)[((size_t)(bb * TP + tt + 2)) * N + col] = f2bf(gelu_f(acc[mf][nf][rr]));
        } else {
          atomicAdd((float*)outp + (size_t)row * N + col, acc[mf][nf][rr]);
        }
      }
    }
  }
}

// ---------------------------------------------------------------------------
// MFMA flash attention, 128-row Q-blocks x 8 waves (512 thr). Each wave owns
// 16 q-rows; K/V tiles (64 keys) staged once per 128 q-rows (halves K/V
// restage traffic vs 64-row blocks). Causal mask via exact srow>qrow
// predicate (covers the two partial diagonal tiles). LDS 36.9 KB -> 4
// blocks/CU.
__global__ __launch_bounds__(512)
void attn_mfma(const u16* __restrict__ qkv, const u16* __restrict__ vT,
               const unsigned char* __restrict__ mask, u16* __restrict__ y)
{
  const int qb = blockIdx.x, h = blockIdx.y, b = blockIdx.z;
  const int q0 = qb * 128;
  const int tid = threadIdx.x;

  if (mask[b * T_SEQ + q0]){   // monotone suffix mask; 1536 % 128 == 0
    int r = tid >> 2, c4 = (tid & 3) * 16;
    u16* yp = y + (size_t)(b * T_SEQ + q0 + r) * D_MODEL + h * DH + c4;
    ushort4 z = {0, 0, 0, 0};
    #pragma unroll
    for (int c = 0; c < 4; ++c) *(ushort4*)(yp + c * 4) = z;
    return;
  }

  const int w = tid >> 6, lane = tid & 63;
  const int quad = lane >> 4, lr = lane & 15;

  __shared__ u16 Ks[64 * 72];    // [key][dh]
  __shared__ u16 Vs[64 * 72];    // [dh][key]
  __shared__ u16 Ps[128 * 72];   // [query][key]

  bf16x8 aq0, aq1;               // Q A-frags, held all kernel
  {
    const u16* qp = qkv + (size_t)(b * T_SEQ + q0 + w * 16 + lr) * 3072 + h * DH + quad * 8;
    aq0 = *(const bf16x8*)qp;
    aq1 = *(const bf16x8*)(qp + 32);
  }

  f32x4 acc_o[4];
  #pragma unroll
  for (int i = 0; i < 4; ++i){ f32x4 z = {0.f,0.f,0.f,0.f}; acc_o[i] = z; }
  float mrow[4] = {-1e30f, -1e30f, -1e30f, -1e30f};
  float lrow[4] = {0.f, 0.f, 0.f, 0.f};

  const int sr = tid >> 3, sg = tid & 7;   // staging: 512 thr cover 64 rows x 8 groups

  const int ntiles = 2 * qb + 2;
  for (int it = 0; it < ntiles; ++it){
    const int s0 = it * 64;
    {
      *(uint4*)&Ks[sr * 72 + sg * 8] =
        *(const uint4*)(qkv + (size_t)(b * T_SEQ + s0 + sr) * 3072 + D_MODEL + h * DH + sg * 8);
      *(uint4*)&Vs[sr * 72 + sg * 8] =
        *(const uint4*)(vT + ((size_t)(b * NHEAD + h) * 64 + sr) * T_SEQ + s0 + sg * 8);
    }
    __syncthreads();

    // S = Q K^T (fp32 acc)
    f32x4 accs[4];
    #pragma unroll
    for (int nt = 0; nt < 4; ++nt){
      f32x4 z = {0.f, 0.f, 0.f, 0.f};
      bf16x8 bk0 = *(const bf16x8*)&Ks[(nt * 16 + lr) * 72 + quad * 8];
      bf16x8 bk1 = *(const bf16x8*)&Ks[(nt * 16 + lr) * 72 + quad * 8 + 32];
      z = __builtin_amdgcn_mfma_f32_16x16x32_bf16(aq0, bk0, z, 0, 0, 0);
      z = __builtin_amdgcn_mfma_f32_16x16x32_bf16(aq1, bk1, z, 0, 0, 0);
      accs[nt] = z;
    }

    float sv[4][4], mx[4];
    #pragma unroll
    for (int rr = 0; rr < 4; ++rr) mx[rr] = -1e30f;
    #pragma unroll
    for (int nt = 0; nt < 4; ++nt){
      int srow = s0 + nt * 16 + lr;
      #pragma unroll
      for (int rr = 0; rr < 4; ++rr){
        int qrow = q0 + w * 16 + quad * 4 + rr;
        float s = accs[nt][rr] * 0.125f;
        if (srow > qrow) s = -1e30f;
        sv[nt][rr] = s;
        mx[rr] = fmaxf(mx[rr], s);
      }
    }
    #pragma unroll
    for (int o = 1; o < 16; o <<= 1){
      #pragma unroll
      for (int rr = 0; rr < 4; ++rr) mx[rr] = fmaxf(mx[rr], __shfl_xor(mx[rr], o));
    }
    float alpha[4], psum[4];
    #pragma unroll
    for (int rr = 0; rr < 4; ++rr){
      float mnew = fmaxf(mrow[rr], mx[rr]);
      alpha[rr] = __expf(mrow[rr] - mnew);
      mrow[rr] = mnew;
      psum[rr] = 0.f;
    }
    #pragma unroll
    for (int nt = 0; nt < 4; ++nt){
      #pragma unroll
      for (int rr = 0; rr < 4; ++rr){
        float p = __expf(sv[nt][rr] - mrow[rr]);
        psum[rr] += p;
        Ps[(w * 16 + quad * 4 + rr) * 72 + nt * 16 + lr] = f2bf(p);
      }
    }
    #pragma unroll
    for (int o = 1; o < 16; o <<= 1){
      #pragma unroll
      for (int rr = 0; rr < 4; ++rr) psum[rr] += __shfl_xor(psum[rr], o);
    }
    #pragma unroll
    for (int rr = 0; rr < 4; ++rr) lrow[rr] = lrow[rr] * alpha[rr] + psum[rr];
    #pragma unroll
    for (int nt = 0; nt < 4; ++nt)
      #pragma unroll
      for (int rr = 0; rr < 4; ++rr) acc_o[nt][rr] *= alpha[rr];

    // O += P V  (P rows written/read by the same wave; DS pipe is in-order)
    bf16x8 ap0 = *(const bf16x8*)&Ps[(w * 16 + lr) * 72 + quad * 8];
    bf16x8 ap1 = *(const bf16x8*)&Ps[(w * 16 + lr) * 72 + quad * 8 + 32];
    #pragma unroll
    for (int nt = 0; nt < 4; ++nt){
      bf16x8 bv0 = *(const bf16x8*)&Vs[(nt * 16 + lr) * 72 + quad * 8];
      bf16x8 bv1 = *(const bf16x8*)&Vs[(nt * 16 + lr) * 72 + quad * 8 + 32];
      acc_o[nt] = __builtin_amdgcn_mfma_f32_16x16x32_bf16(ap0, bv0, acc_o[nt], 0, 0, 0);
      acc_o[nt] = __builtin_amdgcn_mfma_f32_16x16x32_bf16(ap1, bv1, acc_o[nt], 0, 0, 0);
    }
    __syncthreads();   // before next tile's staging overwrites Ks/Vs
  }

  #pragma unroll
  for (int rr = 0; rr < 4; ++rr){
    int qg = q0 + w * 16 + quad * 4 + rr;
    float inv = 1.0f / lrow[rr];
    bool rm = mask[b * T_SEQ + qg] != 0;
    #pragma unroll
    for (int nt = 0; nt < 4; ++nt){
      float v = rm ? 0.f : acc_o[nt][rr] * inv;
      y[(size_t)(b * T_SEQ + qg) * D_MODEL + h * DH + nt * 16 + lr] = f2bf(v);
    }
  }
}

// ---------------------------------------------------------------------------
extern "C" void kernel_launch(void* const* d_in, const int* in_sizes, int n_in,
                              void* d_out, int out_size, void* d_ws, size_t ws_size,
                              hipStream_t stream)
{
  const void* x       = d_in[0];
  const unsigned char* xmask_raw = (const unsigned char*)d_in[1];
  const void* pos     = d_in[2];
  const void* w_qkv   = d_in[3];
  const void* w_o     = d_in[4];
  const void* ln1_g   = d_in[5];
  const void* ln1_b   = d_in[6];
  const void* ln2_g   = d_in[7];
  const void* ln2_b   = d_in[8];
  const void* conv1_w = d_in[9];
  const void* conv2_w = d_in[10];

  char* ws = (char*)d_ws;
  size_t o = 0;
  auto alloc = [&](size_t bytes){ size_t cur = o; o += (bytes + 255) & ~(size_t)255; return cur; };
  unsigned* flags = (unsigned*)(ws + alloc(256));
  unsigned char* maskc = (unsigned char*)(ws + alloc(2 * T_SEQ));
  float* x1   = (float*)(ws + alloc((size_t)2 * T_SEQ * D_MODEL * 4));
  char* h2slab = ws + alloc((size_t)2 * TP * D_MODEL * 2);
  u16* g1pad  = (u16*)(ws + alloc((size_t)2 * TP * F_FF * 2));
  u16* slabA  = (u16*)(ws + alloc((size_t)4096 * 3072 * 2));
  u16* qy     = (u16*)(ws + alloc((size_t)4096 * 1024 * 2));
  char* vslab = ws + alloc((size_t)4096 * 1024 * 4);
  u16* vt     = (u16*)vslab;
  float* xc   = (float*)vslab;

  u16* wqkv_c = (u16*)h2slab;
  u16* wo_c   = (u16*)h2slab + (size_t)3072 * 1024;
  u16* h2pad  = (u16*)h2slab;
  u16* qin    = qy;
  u16* qkvb   = slabA;
  u16* yb     = qy;
  u16* W1cat  = slabA;
  u16* W2cat  = slabA;

  detect_dtype<<<1, 64, 0, stream>>>((const u16*)x, flags);
  canon_mask<<<16, 256, 0, stream>>>(xmask_raw, maskc);
  cast_any2bf<<<3072 * 1024 / 4 / 256, 256, 0, stream>>>(w_qkv, wqkv_c, 3072 * 1024, flags);
  cast_any2bf<<<1024 * 1024 / 4 / 256, 256, 0, stream>>>(w_o, wo_c, 1024 * 1024, flags);
  ln_kernel<0><<<4096, 256, 0, stream>>>(x, ln1_g, ln1_b, pos, qin, 1, 0, flags);
  gemm_bt<0><<<dim3(24, 32), 256, 0, stream>>>(qin, wqkv_c, vt, qkvb,
                                               3072, 1024, 10, 1, (long)T_SEQ * 1024, flags);
  // attn: 128-row Q-blocks, 8 waves
  attn_mfma<<<dim3(16, 16, 2), 512, 0, stream>>>(qkvb, vt, maskc, yb);
  gemm_bt<1><<<dim3(8, 32), 256, 0, stream>>>(yb, wo_c, x, x1,
                                              1024, 1024, 10, 1, (long)T_SEQ * 1024, flags);
  hipMemsetAsync(xc, 0, (size_t)4096 * 1024 * 4, stream);
  conv_w_split<<<4096 * 1024 / 256, 256, 0, stream>>>(conv1_w, W1cat, 10, flags);
  zero_pads<<<64, 256, 0, stream>>>(h2pad, g1pad);
  ln_kernel<1><<<4096, 256, 0, stream>>>(x1, ln2_g, ln2_b, nullptr, h2pad, 0, 1, flags);
  // g1 = gelu(causal_conv1(h2)) : R7 pipelined GEMM + XCD-locality decode
  gemm8<2><<<dim3(256, 1, 1), 512, 0, stream>>>(h2pad, W1cat, g1pad,
                                                4096, 1024, 3072, 96, (long)TP * 1024);
  conv_w_split<<<4096 * 1024 / 256, 256, 0, stream>>>(conv2_w, W2cat, 12, flags);
  // conv2 as plain linear-K GEMM, split-K x4 via XCD decode, atomic fp32.
  gemm8<4><<<dim3(256, 1, 1), 512, 0, stream>>>(g1pad, W2cat, xc,
                                                1024, 4096, 12288, 96, (long)TP * 4096);
  cast_out<<<4096 * 1024 / 4 / 256, 256, 0, stream>>>(xc, x1, d_out, 4096 * 1024, flags);
}